// Round 4
// baseline (199.148 us; speedup 1.0000x reference)
//
#include <hip/hip_runtime.h>
#include <math.h>
#include <limits.h>

#define B_   64
#define O_   512
#define N_   784
#define NBLK 256           // 64 rows x 4  == exactly one block per CU
#define NCH  8
#define CHJ  98            // NCH * CHJ == N_
#define BIGV 1e10f

// Single fused kernel:
//  phase 1: e = exp(1.79 x); stable argsort via rank/counting sort (4 thr/rank,
//           shfl combine); w transpose rides on the spare 240 threads/block.
//  software grid barrier (device-scope atomic + fences; counter reset by a
//  hipMemsetAsync each launch -> deterministic across graph replays).
//  phase 2: per-(b, o-group-128) first-hit scan, 8 j-chunks in-block, combine
//           via LDS (no partial buffers, no extra kernel).
__global__ __launch_bounds__(1024) void snn_fused(const float* __restrict__ x,
                                                  const float* __restrict__ w,
                                                  float* __restrict__ out,
                                                  float* __restrict__ wT,
                                                  float* __restrict__ s_g,
                                                  int* __restrict__ i_g,
                                                  int* __restrict__ cnt)
{
    __shared__ __attribute__((aligned(16))) float e_sh[N_];
    __shared__ float ls[N_];
    __shared__ int   li[N_];
    __shared__ int   jfs[NCH][128];

    const int tid = threadIdx.x;
    const int bid = blockIdx.x;
    const int b   = bid >> 2;      // row (phase 1) == batch (phase 2)
    const int q   = bid & 3;       // rank quarter (phase 1) == o-group (phase 2)

    // ------------------ phase 1 ------------------
    if (tid < N_) {
        e_sh[tid] = expf(x[b * N_ + tid] * 1.79f);
    } else {
        // transpose: wT[n][o] = w[o][n], flat t = n*512 + o
        const int nt = 1024 - N_;                  // 240 spare threads
        for (int t = bid * nt + (tid - N_); t < O_ * N_; t += NBLK * nt)
            wT[t] = w[(t & (O_ - 1)) * N_ + (t >> 9)];
    }
    __syncthreads();

    if (tid < N_) {
        // rank(i) = #{k: e[k]<e[i] || (e[k]==e[i] && k<i)} == stable argsort perm
        const int   i    = q * 196 + (tid >> 2);
        const int   part = tid & 3;                // 4 threads per rank
        const float ei   = e_sh[i];
        int r = 0;
        const float4* e4 = (const float4*)e_sh;
        #pragma unroll 7
        for (int kk = 0; kk < 49; ++kk) {
            int    k4 = part * 49 + kk;
            float4 v  = e4[k4];                    // LDS broadcast-ish, conflict-light
            int    k  = k4 * 4;
            r += (v.x < ei || (v.x == ei && (k + 0) < i)) ? 1 : 0;
            r += (v.y < ei || (v.y == ei && (k + 1) < i)) ? 1 : 0;
            r += (v.z < ei || (v.z == ei && (k + 2) < i)) ? 1 : 0;
            r += (v.w < ei || (v.w == ei && (k + 3) < i)) ? 1 : 0;
        }
        r += __shfl_xor(r, 1);
        r += __shfl_xor(r, 2);
        if (part == 0) {                           // ranks are a bijection
            s_g[b * N_ + r] = ei;
            i_g[b * N_ + r] = i;
        }
    }

    // ------------------ grid barrier ------------------
    __threadfence();                               // agent fence: L2 writeback
    __syncthreads();
    if (tid == 0) {
        __hip_atomic_fetch_add(cnt, 1, __ATOMIC_ACQ_REL, __HIP_MEMORY_SCOPE_AGENT);
        while (__hip_atomic_load(cnt, __ATOMIC_ACQUIRE, __HIP_MEMORY_SCOPE_AGENT) < NBLK)
            __builtin_amdgcn_s_sleep(2);
    }
    __syncthreads();
    __threadfence();                               // agent fence: invalidate stale

    // ------------------ phase 2 ------------------
    if (tid < N_) {
        ls[tid] = s_g[b * N_ + tid];
        li[tid] = i_g[b * N_ + tid];
    }
    __syncthreads();

    const int c     = tid >> 7;                    // j-chunk 0..7 (uniform per wave)
    const int o_off = tid & 127;
    const int o     = q * 128 + o_off;             // waves span 64 consecutive o

    int   jf = INT_MAX;                            // global j of first hit
    float wprev, mulprev;
    int   jlo, jhi;
    if (c == 0) {
        // j = 0: ws_sum = w0, inp_shift = +inf
        float w0   = wT[li[0] * O_ + o];
        float mul0 = ls[0] * w0;
        if ((mul0 < INFINITY) && (w0 > 1.0f)) jf = 0;
        wprev = w0; mulprev = mul0;
        jlo = 1; jhi = CHJ;
    } else {
        int j0  = c * CHJ;
        wprev   = wT[li[j0 - 1] * O_ + o];
        mulprev = ls[j0 - 1] * wprev;
        jlo = j0; jhi = j0 + CHJ;
    }

    #pragma unroll 2
    for (int j = jlo; j < jhi; ++j) {
        float wj    = wT[li[j] * O_ + o];          // coalesced 256B/wave gather
        float sj    = ls[j];                       // LDS broadcast
        float shift = ls[j - 1];
        float mulj  = sj * wj;
        float ws    = wj + wprev;
        float wim   = mulj + mulprev;
        float den   = fminf(fmaxf(ws - 1.0f, 1e-10f), BIGV);
        bool  cond  = (wim < shift * den) && (ws > 1.0f);   // div-free (den > 0)
        if (cond) jf = min(jf, j);
        wprev = wj; mulprev = mulj;
    }
    jfs[c][o_off] = jf;
    __syncthreads();

    if (tid < 128) {
        const int oo = q * 128 + tid;
        int jm = INT_MAX;
        #pragma unroll
        for (int cc = 0; cc < NCH; ++cc) jm = min(jm, jfs[cc][tid]);

        float res;
        if (jm == INT_MAX && BIGV < ls[N_ - 1]) {
            res = BIGV;                            // j = N tail hit
        } else if (jm == INT_MAX || jm == 0) {
            float w0   = wT[li[0] * O_ + oo];      // out_all[0] default / j=0 hit
            float mul0 = ls[0] * w0;
            float den0 = fminf(fmaxf(w0 - 1.0f, 1e-10f), BIGV);
            res = mul0 / den0;
        } else {
            float wj  = wT[li[jm] * O_ + oo];      // recompute winner's value
            float wp  = wT[li[jm - 1] * O_ + oo];
            float a   = ls[jm] * wj;
            float bb  = ls[jm - 1] * wp;
            float den = fminf(fmaxf((wj + wp) - 1.0f, 1e-10f), BIGV);
            res = (a + bb) / den;
        }
        out[b * O_ + oo] = res;
    }
}

extern "C" void kernel_launch(void* const* d_in, const int* in_sizes, int n_in,
                              void* d_out, int out_size, void* d_ws, size_t ws_size,
                              hipStream_t stream)
{
    const float* x = (const float*)d_in[0];   // [B, N]
    const float* w = (const float*)d_in[1];   // [O, N]
    float* out = (float*)d_out;               // [B, O]

    char* ws = (char*)d_ws;
    size_t off = 0;
    float* wT  = (float*)(ws + off); off += (size_t)N_ * O_ * sizeof(float);
    float* s   = (float*)(ws + off); off += (size_t)B_ * N_ * sizeof(float);
    int*   ix  = (int*)  (ws + off); off += (size_t)B_ * N_ * sizeof(int);
    int*   cnt = (int*)  (ws + off); off += sizeof(int);

    // reset barrier counter every launch -> graph replays are deterministic
    hipMemsetAsync(cnt, 0, sizeof(int), stream);

    hipLaunchKernelGGL(snn_fused, dim3(NBLK), dim3(1024), 0, stream,
                       x, w, out, wT, s, ix, cnt);
}

// Round 5
// 36.737 us; speedup vs baseline: 5.4209x; 5.4209x over previous
//
#include <hip/hip_runtime.h>
#include <math.h>

#define B_   64
#define O_   512
#define N_   784
#define BIGV 1e10f

#define RANK_BLOCKS   (B_ * 4)                    // 64 rows x 4 chunks of 196
#define TRANS_BLOCKS  ((O_ * N_) / 256)           // 1568
#define FLAG_BLOCKS   8                           // 8 blocks x 4 waves x 16 rows
#define CHUNK_I       196

// ---------------------------------------------------------------------------
// Kernel 1 (fused grid): stable argsort via rank sort + w transpose + per-o
// "possible" flag.
//   rank(i) = #{k : e[k]<e[i] || (e[k]==e[i] && k<i)} == stable argsort perm.
//   flag[o] = (2*max_n w[o,n] > 1): only such rows can EVER satisfy
//   ws_sum > 1 at j<N (ws_sum is a sum of two distinct-row... two adjacent
//   gathered weights <= 2*wmax). Exact for all inputs.
// ---------------------------------------------------------------------------
__global__ __launch_bounds__(256) void snn_prep(const float* __restrict__ x,
                                                const float* __restrict__ w,
                                                float* __restrict__ s_out,
                                                int* __restrict__ i_out,
                                                float* __restrict__ wT,
                                                int* __restrict__ flag)
{
    int bid = blockIdx.x;

    if (bid >= RANK_BLOCKS + TRANS_BLOCKS) {
        // -------- flag part: flag[r] = (2*rowmax(w[r,:]) > 1) --------
        const int f    = bid - RANK_BLOCKS - TRANS_BLOCKS;
        const int wave = threadIdx.x >> 6;
        const int lane = threadIdx.x & 63;
        const int gw   = f * 4 + wave;             // 0..31
        for (int r = gw * 16; r < gw * 16 + 16; ++r) {
            float m = 0.0f;
            for (int k = lane; k < N_; k += 64)    // coalesced row read
                m = fmaxf(m, w[r * N_ + k]);
            #pragma unroll
            for (int d = 1; d < 64; d <<= 1)
                m = fmaxf(m, __shfl_xor(m, d));
            if (lane == 0) flag[r] = (m + m > 1.0f) ? 1 : 0;
        }
        return;
    }

    if (bid >= RANK_BLOCKS) {
        // -------- transpose part: wT[n][o] = w[o][n] --------
        int t = (bid - RANK_BLOCKS) * 256 + threadIdx.x;   // t indexes wT[N][O]
        int n = t >> 9;            // / O_
        int o = t & (O_ - 1);      // % O_
        wT[t] = w[o * N_ + n];     // coalesced write; strided read (L2-resident)
        return;
    }

    // -------- rank part --------
    __shared__ __attribute__((aligned(16))) float se[N_];
    const int b     = bid >> 2;
    const int chunk = bid & 3;

    for (int i = threadIdx.x; i < N_; i += 256)
        se[i] = expf(x[b * N_ + i] * 1.79f);
    __syncthreads();

    if (threadIdx.x < CHUNK_I) {
        const int i  = chunk * CHUNK_I + threadIdx.x;
        const float ei = se[i];
        int r = 0;
        const float4* se4 = (const float4*)se;
        #pragma unroll 4
        for (int k4 = 0; k4 < N_ / 4; ++k4) {
            float4 v = se4[k4];    // LDS broadcast: all lanes same addr
            int k = k4 * 4;
            r += (v.x < ei || (v.x == ei && (k + 0) < i)) ? 1 : 0;
            r += (v.y < ei || (v.y == ei && (k + 1) < i)) ? 1 : 0;
            r += (v.z < ei || (v.z == ei && (k + 2) < i)) ? 1 : 0;
            r += (v.w < ei || (v.w == ei && (k + 3) < i)) ? 1 : 0;
        }
        s_out[b * N_ + r] = ei;    // ranks are a bijection -> exact scatter
        i_out[b * N_ + r] = i;
    }
}

// ---------------------------------------------------------------------------
// Kernel 2: per-(b,o) result.
//   Unflagged o (2*wmax <= 1): cond[j] false for all j<N exactly, so
//     out = (BIG < s[N-1]) ? BIG : s0*w0/clip(w0-1, 1e-10, BIG).
//   Flagged o: faithful serial first-hit scan (rare/never on real data).
// ---------------------------------------------------------------------------
__global__ __launch_bounds__(128) void snn_main(const float* __restrict__ wT,
                                                const float* __restrict__ s_in,
                                                const int*  __restrict__ i_in,
                                                const int*  __restrict__ flag,
                                                float* __restrict__ out)
{
    __shared__ float ls[N_];
    __shared__ int   li[N_];
    const int b = blockIdx.x;
    const int o = blockIdx.y * 128 + threadIdx.x;

    for (int i = threadIdx.x; i < N_; i += 128) {
        ls[i] = s_in[b * N_ + i];
        li[i] = i_in[b * N_ + i];
    }
    __syncthreads();

    const float s0   = ls[0];
    const float smax = ls[N_ - 1];
    const float w0   = wT[li[0] * O_ + o];        // coalesced in o
    const float mul0 = s0 * w0;
    const float den0 = fminf(fmaxf(w0 - 1.0f, 1e-10f), BIGV);
    const float oa0  = mul0 / den0;

    float res;
    if (flag[o] == 0) {
        // no j<N can hit; j=N hits iff BIG < s[N-1], else index 0
        res = (BIGV < smax) ? BIGV : oa0;
    } else {
        // faithful full scan
        bool found = (oa0 < INFINITY) && (w0 > 1.0f);
        res = oa0;
        float wprev = w0, mulprev = mul0;
        for (int j = 1; j < N_; ++j) {
            float wj   = wT[li[j] * O_ + o];
            float sj   = ls[j];
            float mulj = sj * wj;
            float ws   = wj + wprev;
            float wim  = mulj + mulprev;
            float den  = fminf(fmaxf(ws - 1.0f, 1e-10f), BIGV);
            float oa   = wim / den;
            bool cond  = (oa < ls[j - 1]) && (ws > 1.0f);
            if (cond && !found) { res = oa; found = true; }
            wprev = wj; mulprev = mulj;
        }
        if (!found && (BIGV < smax)) res = BIGV;
    }

    out[b * O_ + o] = res;
}

extern "C" void kernel_launch(void* const* d_in, const int* in_sizes, int n_in,
                              void* d_out, int out_size, void* d_ws, size_t ws_size,
                              hipStream_t stream)
{
    const float* x = (const float*)d_in[0];   // [B, N]
    const float* w = (const float*)d_in[1];   // [O, N]
    float* out = (float*)d_out;               // [B, O]

    char* ws = (char*)d_ws;
    size_t off = 0;
    float* wT = (float*)(ws + off); off += (size_t)N_ * O_ * sizeof(float);
    float* s  = (float*)(ws + off); off += (size_t)B_ * N_ * sizeof(float);
    int*   ix = (int*)  (ws + off); off += (size_t)B_ * N_ * sizeof(int);
    int*   fl = (int*)  (ws + off); off += (size_t)O_ * sizeof(int);

    hipLaunchKernelGGL(snn_prep, dim3(RANK_BLOCKS + TRANS_BLOCKS + FLAG_BLOCKS),
                       dim3(256), 0, stream, x, w, s, ix, wT, fl);

    hipLaunchKernelGGL(snn_main, dim3(B_, O_ / 128), dim3(128), 0, stream,
                       wT, s, ix, fl, out);
}

// Round 6
// 26.572 us; speedup vs baseline: 7.4947x; 1.3825x over previous
//
#include <hip/hip_runtime.h>
#include <math.h>

#define B_   64
#define O_   512
#define N_   784
#define M_   1024
#define BIGV 1e10f

// One kernel, no workspace. Block = (b, quarter q of 128 o's), 512 threads.
//  A: stable min/argmin + max of e = exp(1.79*x[b,:])  (block-local reduce)
//  B: flag[o] = (2*rowmax(w[o,:]) > 1) for this block's 128 o's (4 thr/row)
//     -- only flagged o can EVER satisfy ws_sum > 1 at j < N, since
//        ws_sum = wg[j]+wg[j-1] <= 2*rowmax (RN addition is monotone).
//  C: unflagged o: index = N if BIG < smax else 0  ->
//        out = BIG < smax ? BIG : s0*w0 / clip(w0-1, 1e-10, BIG), w0 = w[o,i0]
//  D: (cold, block-uniform) flagged o: bitonic-sort row in LDS + faithful scan.
__global__ __launch_bounds__(512) void snn_one(const float* __restrict__ x,
                                               const float* __restrict__ w,
                                               float* __restrict__ out)
{
    __shared__ float wmn[8];
    __shared__ int   wmi[8];
    __shared__ float wmx[8];
    __shared__ int   flags[128];
    __shared__ float sk[M_];          // cold path only
    __shared__ int   sv[M_];          // cold path only

    const int tid   = threadIdx.x;
    const int b     = blockIdx.x >> 2;
    const int q     = blockIdx.x & 3;
    const int obase = q * 128;

    // ---------------- phase A: e-row reduce ----------------
    float mn = __builtin_inff(); int mni = 0; float mx = 0.0f;
    for (int i = tid; i < N_; i += 512) {
        float v = expf(x[b * N_ + i] * 1.79f);
        if (v < mn) { mn = v; mni = i; }          // ascending i => first idx kept
        mx = fmaxf(mx, v);
    }
    #pragma unroll
    for (int d = 1; d < 64; d <<= 1) {
        float omn = __shfl_xor(mn, d);
        int   omi = __shfl_xor(mni, d);
        float omx = __shfl_xor(mx, d);
        if (omn < mn || (omn == mn && omi < mni)) { mn = omn; mni = omi; }
        mx = fmaxf(mx, omx);
    }
    if ((tid & 63) == 0) { wmn[tid >> 6] = mn; wmi[tid >> 6] = mni; wmx[tid >> 6] = mx; }
    __syncthreads();
    float s0 = wmn[0]; int i0 = wmi[0]; float smax = wmx[0];
    #pragma unroll
    for (int k = 1; k < 8; ++k) {                 // uniform, LDS broadcast
        float v = wmn[k]; int vi = wmi[k];
        if (v < s0 || (v == s0 && vi < i0)) { s0 = v; i0 = vi; }
        smax = fmaxf(smax, wmx[k]);
    }

    // ---------------- phase B: flags (4 threads per w-row) ----------------
    const int ol = tid >> 2, part = tid & 3;      // 128 rows x 4 parts
    {
        const float4* wr = (const float4*)(w + (size_t)(obase + ol) * N_ + part * 196);
        float m = 0.0f;
        #pragma unroll 7
        for (int kk = 0; kk < 49; ++kk) {         // 196 floats per part, streaming
            float4 v = wr[kk];
            m = fmaxf(m, fmaxf(fmaxf(v.x, v.y), fmaxf(v.z, v.w)));
        }
        m = fmaxf(m, __shfl_xor(m, 1));
        m = fmaxf(m, __shfl_xor(m, 2));
        if (part == 0) flags[ol] = (m + m > 1.0f) ? 1 : 0;
    }
    int anyflag = __syncthreads_or((part == 0 && tid < 512) ? ((tid >> 2) < 128 ? 0 : 0) : 0);
    // (separate or-reduce below; the call above only serves as the barrier-or seed)
    // NOTE: flags[] is now visible; fold its content into anyflag properly:
    anyflag |= __syncthreads_or(tid < 128 ? flags[tid] : 0);

    // ---------------- phase C: fast path ----------------
    if (tid < 128 && !flags[tid]) {
        const int o  = obase + tid;
        float w0   = w[(size_t)o * N_ + i0];      // one gather per output
        float mul0 = s0 * w0;
        float den0 = fminf(fmaxf(w0 - 1.0f, 1e-10f), BIGV);
        float oa0  = mul0 / den0;
        out[b * O_ + o] = (BIGV < smax) ? BIGV : oa0;
    }

    // ---------------- phase D: cold exact fallback ----------------
    if (anyflag) {
        for (int i = tid; i < M_; i += 512) {
            sk[i] = (i < N_) ? expf(x[b * N_ + i] * 1.79f) : __builtin_inff();
            sv[i] = i;
        }
        __syncthreads();
        for (int k = 2; k <= M_; k <<= 1) {
            for (int j = k >> 1; j > 0; j >>= 1) {
                int i = ((tid & ~(j - 1)) << 1) | (tid & (j - 1));
                int p = i | j;
                float ki = sk[i], kp = sk[p];
                int   vi = sv[i], vp = sv[p];
                bool gt = (ki > kp) || (ki == kp && vi > vp);
                bool up = ((i & k) == 0);
                if (gt == up) { sk[i] = kp; sk[p] = ki; sv[i] = vp; sv[p] = vi; }
                __syncthreads();
            }
        }
        if (tid < 128 && flags[tid]) {
            const int o = obase + tid;
            const float* wrow = w + (size_t)o * N_;
            float w0   = wrow[sv[0]];
            float mul0 = sk[0] * w0;
            float den0 = fminf(fmaxf(w0 - 1.0f, 1e-10f), BIGV);
            float oa0  = mul0 / den0;
            bool found = (oa0 < __builtin_inff()) && (w0 > 1.0f);
            float res  = oa0;
            float wprev = w0, mulprev = mul0;
            for (int j = 1; j < N_; ++j) {
                float wj   = wrow[sv[j]];
                float sj   = sk[j];
                float mulj = sj * wj;
                float ws   = wj + wprev;
                float wim  = mulj + mulprev;
                float den  = fminf(fmaxf(ws - 1.0f, 1e-10f), BIGV);
                float oa   = wim / den;
                bool cond  = (oa < sk[j - 1]) && (ws > 1.0f);
                if (cond && !found) { res = oa; found = true; }
                wprev = wj; mulprev = mulj;
            }
            if (!found && BIGV < smax) res = BIGV;
            out[b * O_ + o] = res;
        }
    }
}

extern "C" void kernel_launch(void* const* d_in, const int* in_sizes, int n_in,
                              void* d_out, int out_size, void* d_ws, size_t ws_size,
                              hipStream_t stream)
{
    const float* x = (const float*)d_in[0];   // [B, N]
    const float* w = (const float*)d_in[1];   // [O, N]
    float* out = (float*)d_out;               // [B, O]

    hipLaunchKernelGGL(snn_one, dim3(B_ * 4), dim3(512), 0, stream, x, w, out);
}

// Round 7
// 13.276 us; speedup vs baseline: 15.0000x; 2.0014x over previous
//
#include <hip/hip_runtime.h>
#include <math.h>

#define B_   64
#define O_   512
#define N_   784
#define M_   1024
#define BIGV 1e10f

// ---------------------------------------------------------------------------
// Kernel 1: flag[o] = (2 * max_n w[o,n] > 1).  One wave per row, contiguous
// 1KB-per-instruction reads (float4 x 64 lanes), shfl-reduce. 1.6 MB total.
// Only flagged rows can EVER satisfy ws_sum > 1 at j < N:
//   ws = RN(wg[j] + wg[j-1]) <= RN(m + m) = 2m  (RN monotone, 2m exact),
// so 2m <= 1  =>  ws > 1 is false for all j, and w0 > 1 false at j = 0.
// ---------------------------------------------------------------------------
__global__ __launch_bounds__(128) void snn_flags(const float* __restrict__ w,
                                                 int* __restrict__ flag)
{
    const int row  = blockIdx.x * 2 + (threadIdx.x >> 6);   // 256 blocks x 2 waves
    const int lane = threadIdx.x & 63;
    const float4* wr = (const float4*)(w + (size_t)row * N_);
    float m = 0.0f;
    #pragma unroll
    for (int it = 0; it < 4; ++it) {
        int idx = lane + it * 64;                 // 196 float4s per row
        if (idx < 196) {
            float4 v = wr[idx];
            m = fmaxf(m, fmaxf(fmaxf(v.x, v.y), fmaxf(v.z, v.w)));
        }
    }
    #pragma unroll
    for (int d = 1; d < 64; d <<= 1)
        m = fmaxf(m, __shfl_xor(m, d));
    if (lane == 0) flag[row] = (m + m > 1.0f) ? 1 : 0;
}

// ---------------------------------------------------------------------------
// Kernel 2: block = (b, quarter q of 128 o's), 512 threads.
//  A: stable min/argmin + max of e = exp(1.79*x[b,:])
//  C: unflagged o: index = N if BIG < smax else 0  ->
//       out = BIG < smax ? BIG : s0*w0 / clip(w0-1, 1e-10, BIG),  w0 = w[o,i0]
//  D: (cold, block-uniform) flagged o: bitonic sort in LDS + faithful scan.
// ---------------------------------------------------------------------------
__global__ __launch_bounds__(512) void snn_main(const float* __restrict__ x,
                                                const float* __restrict__ w,
                                                const int* __restrict__ flag,
                                                float* __restrict__ out)
{
    __shared__ float wmn[8];
    __shared__ int   wmi[8];
    __shared__ float wmx[8];
    __shared__ int   flags[128];
    __shared__ float sk[M_];          // cold path only
    __shared__ int   sv[M_];          // cold path only

    const int tid   = threadIdx.x;
    const int b     = blockIdx.x >> 2;
    const int q     = blockIdx.x & 3;
    const int obase = q * 128;

    // ---------------- phase A: e-row reduce ----------------
    float mn = __builtin_inff(); int mni = 0; float mx = 0.0f;
    for (int i = tid; i < N_; i += 512) {
        float v = expf(x[b * N_ + i] * 1.79f);
        if (v < mn) { mn = v; mni = i; }          // ascending i per thread
        mx = fmaxf(mx, v);
    }
    if (tid < 128) flags[tid] = flag[obase + tid];
    #pragma unroll
    for (int d = 1; d < 64; d <<= 1) {
        float omn = __shfl_xor(mn, d);
        int   omi = __shfl_xor(mni, d);
        float omx = __shfl_xor(mx, d);
        if (omn < mn || (omn == mn && omi < mni)) { mn = omn; mni = omi; }
        mx = fmaxf(mx, omx);
    }
    if ((tid & 63) == 0) { wmn[tid >> 6] = mn; wmi[tid >> 6] = mni; wmx[tid >> 6] = mx; }
    int anyflag = __syncthreads_or(tid < 128 ? flags[tid] : 0);

    float s0 = wmn[0]; int i0 = wmi[0]; float smax = wmx[0];
    #pragma unroll
    for (int k = 1; k < 8; ++k) {                 // uniform, LDS broadcast
        float v = wmn[k]; int vi = wmi[k];
        if (v < s0 || (v == s0 && vi < i0)) { s0 = v; i0 = vi; }
        smax = fmaxf(smax, wmx[k]);
    }

    // ---------------- phase C: fast path ----------------
    if (tid < 128 && !flags[tid]) {
        const int o  = obase + tid;
        float w0   = w[(size_t)o * N_ + i0];      // one gather per output
        float mul0 = s0 * w0;
        float den0 = fminf(fmaxf(w0 - 1.0f, 1e-10f), BIGV);
        float oa0  = mul0 / den0;
        out[b * O_ + o] = (BIGV < smax) ? BIGV : oa0;
    }

    // ---------------- phase D: cold exact fallback ----------------
    if (anyflag) {
        for (int i = tid; i < M_; i += 512) {
            sk[i] = (i < N_) ? expf(x[b * N_ + i] * 1.79f) : __builtin_inff();
            sv[i] = i;
        }
        __syncthreads();
        for (int k = 2; k <= M_; k <<= 1) {
            for (int j = k >> 1; j > 0; j >>= 1) {
                int i = ((tid & ~(j - 1)) << 1) | (tid & (j - 1));
                int p = i | j;
                float ki = sk[i], kp = sk[p];
                int   vi = sv[i], vp = sv[p];
                bool gt = (ki > kp) || (ki == kp && vi > vp);
                bool up = ((i & k) == 0);
                if (gt == up) { sk[i] = kp; sk[p] = ki; sv[i] = vp; sv[p] = vi; }
                __syncthreads();
            }
        }
        if (tid < 128 && flags[tid]) {
            const int o = obase + tid;
            const float* wrow = w + (size_t)o * N_;
            float w0   = wrow[sv[0]];
            float mul0 = sk[0] * w0;
            float den0 = fminf(fmaxf(w0 - 1.0f, 1e-10f), BIGV);
            float oa0  = mul0 / den0;
            bool found = (oa0 < __builtin_inff()) && (w0 > 1.0f);
            float res  = oa0;
            float wprev = w0, mulprev = mul0;
            for (int j = 1; j < N_; ++j) {
                float wj   = wrow[sv[j]];
                float sj   = sk[j];
                float mulj = sj * wj;
                float ws   = wj + wprev;
                float wim  = mulj + mulprev;
                float den  = fminf(fmaxf(ws - 1.0f, 1e-10f), BIGV);
                float oa   = wim / den;
                bool cond  = (oa < sk[j - 1]) && (ws > 1.0f);
                if (cond && !found) { res = oa; found = true; }
                wprev = wj; mulprev = mulj;
            }
            if (!found && BIGV < smax) res = BIGV;
            out[b * O_ + o] = res;
        }
    }
}

extern "C" void kernel_launch(void* const* d_in, const int* in_sizes, int n_in,
                              void* d_out, int out_size, void* d_ws, size_t ws_size,
                              hipStream_t stream)
{
    const float* x = (const float*)d_in[0];   // [B, N]
    const float* w = (const float*)d_in[1];   // [O, N]
    float* out = (float*)d_out;               // [B, O]
    int*   fl  = (int*)d_ws;                  // O_ ints

    hipLaunchKernelGGL(snn_flags, dim3(O_ / 2), dim3(128), 0, stream, w, fl);
    hipLaunchKernelGGL(snn_main,  dim3(B_ * 4), dim3(512), 0, stream, x, w, fl, out);
}